// Round 6
// baseline (14991.100 us; speedup 1.0000x reference)
//
#include <hip/hip_runtime.h>
#include <stdint.h>

#define SLEN 4096
#define EDIM 256
#define HD 256
#define G4 1024   // 4*HD
#define KT 20
#define START_ID 18
#define STOP_ID 19
#define NCU 4     // CUs (blocks) per direction

typedef _Float16 half_t;
typedef _Float16 half2_t __attribute__((ext_vector_type(2)));

__device__ __forceinline__ float dot2(uint32_t w, uint32_t h, float acc) {
#if __has_builtin(__builtin_amdgcn_fdot2)
    return __builtin_amdgcn_fdot2(__builtin_bit_cast(half2_t, w),
                                  __builtin_bit_cast(half2_t, h), acc, false);
#else
    half2_t wv = __builtin_bit_cast(half2_t, w);
    half2_t hv = __builtin_bit_cast(half2_t, h);
    acc += (float)wv.x * (float)hv.x;
    acc += (float)wv.y * (float)hv.y;
    return acc;
#endif
}

__device__ __forceinline__ float fsig(float x) { return 1.f / (1.f + __expf(-x)); }
__device__ __forceinline__ float ftanh(float x) { return 1.f - 2.f / (__expf(2.f * x) + 1.f); }

// k_lstm thread geometry (512 thr): w=t>>6, l=t&63, q=l>>4 (k-quarter),
// rp=l&15, ul=rp&7, ga=rp>>3. Unit U = 64*cix + 8*w + ul.
// row_a = ga*256 + U (gate i or f), row_b = (ga+2)*256 + U (gate g or o).
// Each lane: 2 rows x k-quarter [64q, 64q+64) elems = 64 weight dwords in VGPRs.

// ---------------- prep: transpose w_ih into [d][e][o] ----------------
__global__ __launch_bounds__(256) void k_transpose_ih(const float* __restrict__ wf,
                                                      const float* __restrict__ wb,
                                                      float* __restrict__ wT) {
    __shared__ float tile[32][33];
    int d = blockIdx.z;
    const float* w = d ? wb : wf;
    int ob = blockIdx.x * 32;
    int eb = blockIdx.y * 32;
    int tx = threadIdx.x & 31, ty = threadIdx.x >> 5;
#pragma unroll
    for (int r = 0; r < 32; r += 8)
        tile[ty + r][tx] = w[(long)(ob + ty + r) * EDIM + eb + tx];
    __syncthreads();
    float* dst = wT + (long)d * EDIM * G4;
#pragma unroll
    for (int r = 0; r < 32; r += 8)
        dst[(long)(eb + ty + r) * G4 + ob + tx] = tile[tx][ty + r];
}

// ---------------- prep: pack w_hh to fp16 in multi-CU lstm order; zero flags ----------------
__global__ __launch_bounds__(512) void k_pack_hh(const float* __restrict__ whf,
                                                 const float* __restrict__ whb,
                                                 uint32_t* __restrict__ wpack,
                                                 int* __restrict__ flags) {
    int m = blockIdx.x;                 // 0..63 weight-dword slot
    int by = blockIdx.y;                // d = by>>2, cix = by&3
    int d = by >> 2, cix = by & 3;
    const float* W = d ? whb : whf;
    int t = threadIdx.x;
    int w = t >> 6, l = t & 63;
    int q = l >> 4, rp = l & 15, ul = rp & 7, ga = rp >> 3;
    int isB = m >> 5;
    int g = 2 * isB + ga;
    int row = g * 256 + 64 * cix + 8 * w + ul;
    int j = 32 * q + (m & 31);          // W-dword index (fp16 pair j -> elems 2j,2j+1)
    half2_t pk = {(half_t)W[(long)row * HD + 2 * j],
                  (half_t)W[(long)row * HD + 2 * j + 1]};
    wpack[((long)(d * NCU + cix) * 64 + m) * 512 + t] = __builtin_bit_cast(uint32_t, pk);
    if (m == 0 && by == 0 && t < 2 * NCU) flags[t] = 0;   // re-zero every launch (ws poisoned)
}

// ---------------- input projections: zxp[d][s][slot] ----------------
__global__ __launch_bounds__(256) void k_zx(const int* __restrict__ sentence,
                                            const float* __restrict__ embed,
                                            const float* __restrict__ wT,
                                            const float* __restrict__ bf,
                                            const float* __restrict__ bb,
                                            float* __restrict__ zxp) {
    int d = blockIdx.y;
    int s0 = blockIdx.x * 16;
    const float* bias = d ? bb : bf;
    __shared__ float xbuf[16][EDIM];
    int tid = threadIdx.x;
    for (int r = 0; r < 16; r++) {
        int row = sentence[s0 + r];
        xbuf[r][tid] = embed[(long)row * EDIM + tid];
    }
    __syncthreads();
    const float* wTd = wT + (long)d * EDIM * G4;
    for (int og = 0; og < 4; og++) {
        float acc[16];
#pragma unroll
        for (int r = 0; r < 16; r++) acc[r] = 0.f;
        int o = og * 256 + tid;
        for (int e = 0; e < EDIM; e += 4) {
            float w0 = wTd[(long)(e + 0) * G4 + o];
            float w1 = wTd[(long)(e + 1) * G4 + o];
            float w2 = wTd[(long)(e + 2) * G4 + o];
            float w3 = wTd[(long)(e + 3) * G4 + o];
#pragma unroll
            for (int r = 0; r < 16; r++) {
                float4 x4 = *(const float4*)&xbuf[r][e];
                acc[r] += w0 * x4.x + w1 * x4.y + w2 * x4.z + w3 * x4.w;
            }
        }
        float bv = bias[o];
        int U = tid;
        // slot = (cix*8 + w)*32 + ul + 8*(og&1) + 16*(og>>1)
        int slot = (((U >> 6) * 8 + ((U >> 3) & 7)) << 5) + (U & 7) + 8 * (og & 1) + 16 * (og >> 1);
#pragma unroll
        for (int r = 0; r < 16; r++)
            zxp[(long)(d * SLEN + s0 + r) * G4 + slot] = acc[r] + bv;
    }
}

// ---------------- the serial BiLSTM: 2 dirs x 4 CUs, flag-synced per step ----------------
// grid 32: worker iff (b&7)<2 -> dir=b&7, cix=b>>3 (likely same-XCD per dir; perf-only).
// Sync protocol: SINGLE LANE (t==0) does release-post then acquire-spin on the 3
// peers sequentially, in straight program order. (R5 hung: post/spin were on
// different lanes of the same wave -> divergent-branch serialization deadlock.)
__global__ __launch_bounds__(512) void k_lstm(const float* __restrict__ zxp,
                                              const uint32_t* __restrict__ wpack,
                                              const float* __restrict__ h0,
                                              const float* __restrict__ c0,
                                              float* __restrict__ hs,
                                              float* hglob,
                                              int* flags) {
    int b = blockIdx.x;
    int dir = b & 7;
    if (dir >= 2) return;
    int cix = b >> 3;
    int t = threadIdx.x;
    int w = t >> 6, l = t & 63;
    int rp = l & 15, ul = rp & 7;
    int U = 64 * cix + 8 * w + ul;

    uint32_t wreg[64];
    {
        const uint32_t* wp = wpack + ((long)(dir * NCU + cix) * 64) * 512 + t;
#pragma unroll
        for (int m = 0; m < 64; m++) wreg[m] = wp[m * 512];
#pragma unroll
        for (int m = 0; m < 64; m++) asm volatile("" : "+v"(wreg[m]));
    }

    float cst = c0[dir * HD + U];

    const float* zxd = zxp + (long)dir * SLEN * G4 + (cix * 8 + w) * 32;
    float* hsd = hs + (long)dir * SLEN * HD;
    float* hg = hglob + dir * 2 * HD;       // [parity][256] floats
    int* flg = flags + dir * NCU;

    int sx0 = dir ? (SLEN - 1) : 0;
    float zxa_n = zxd[(long)sx0 * G4 + rp];
    float zxb_n = zxd[(long)sx0 * G4 + rp + 16];

    // h(0) from h0: lane l holds h elements 4l..4l+3
    float f0 = h0[dir * HD + 4 * l + 0], f1 = h0[dir * HD + 4 * l + 1];
    float f2 = h0[dir * HD + 4 * l + 2], f3 = h0[dir * HD + 4 * l + 3];

    int srcbase = l & 48;   // 16*q

    for (int s = 0; s < SLEN; s++) {
        int p2 = (s & 1) ^ 1;
        float zxa = zxa_n, zxb = zxb_n;
        if (s + 1 < SLEN) {
            int sxn = dir ? (SLEN - 2 - s) : (s + 1);
            zxa_n = zxd[(long)sxn * G4 + rp];
            zxb_n = zxd[(long)sxn * G4 + rp + 16];
        }
        // pack lane's h elems into fp16 dwords: hx = h-dword 2l, hy = 2l+1
        half2_t h01 = {(half_t)f0, (half_t)f1};
        half2_t h23 = {(half_t)f2, (half_t)f3};
        uint32_t hx = __builtin_bit_cast(uint32_t, h01);
        uint32_t hy = __builtin_bit_cast(uint32_t, h23);

        float za = 0.f, zb = 0.f;
#pragma unroll
        for (int mm = 0; mm < 16; mm++) {
            uint32_t ha = (uint32_t)__shfl((int)hx, srcbase + mm, 64);   // h-dword 32q+2mm
            uint32_t hb = (uint32_t)__shfl((int)hy, srcbase + mm, 64);   // h-dword 32q+2mm+1
            za = dot2(wreg[2 * mm + 0], ha, za);
            za = dot2(wreg[2 * mm + 1], hb, za);
            zb = dot2(wreg[32 + 2 * mm + 0], ha, zb);
            zb = dot2(wreg[32 + 2 * mm + 1], hb, zb);
        }
        // combine the 4 k-quarters (lane bits 4,5)
        za += __shfl_xor(za, 16, 64); za += __shfl_xor(za, 32, 64);
        zb += __shfl_xor(zb, 16, 64); zb += __shfl_xor(zb, 32, 64);
        za += zxa; zb += zxb;
        // gather gates for unit ul: i,f from za (lanes ul, ul+8); g,o from zb
        float zi = __shfl(za, ul, 64);
        float zf = __shfl(za, ul + 8, 64);
        float zg = __shfl(zb, ul, 64);
        float zo = __shfl(zb, ul + 8, 64);
        float ig = fsig(zi), fg = fsig(zf), og = fsig(zo);
        float gg = ftanh(zg);
        cst = fg * cst + ig * gg;
        float hval = og * ftanh(cst);
        if (l < 8) {   // one writer per unit (q=0, ga=0 lanes)
            int sx = dir ? (SLEN - 1 - s) : s;
            hsd[(long)sx * HD + U] = hval;
            __hip_atomic_store(&hg[p2 * HD + U], hval,
                               __ATOMIC_RELAXED, __HIP_MEMORY_SCOPE_AGENT);
        }
        __syncthreads();   // all waves' hg stores drained (vmcnt(0) before barrier)
        if (t == 0) {
            __hip_atomic_store(&flg[cix], s + 1,
                               __ATOMIC_RELEASE, __HIP_MEMORY_SCOPE_AGENT);
#pragma unroll
            for (int pi = 0; pi < NCU - 1; pi++) {
                int peer = pi + (pi >= cix ? 1 : 0);
                while (__hip_atomic_load(&flg[peer], __ATOMIC_ACQUIRE,
                                         __HIP_MEMORY_SCOPE_AGENT) <= s)
                    __builtin_amdgcn_s_sleep(1);
            }
        }
        __syncthreads();
        if (s + 1 < SLEN) {
            const float* src = &hg[p2 * HD + 4 * l];
            f0 = __hip_atomic_load(src + 0, __ATOMIC_RELAXED, __HIP_MEMORY_SCOPE_AGENT);
            f1 = __hip_atomic_load(src + 1, __ATOMIC_RELAXED, __HIP_MEMORY_SCOPE_AGENT);
            f2 = __hip_atomic_load(src + 2, __ATOMIC_RELAXED, __HIP_MEMORY_SCOPE_AGENT);
            f3 = __hip_atomic_load(src + 3, __ATOMIC_RELAXED, __HIP_MEMORY_SCOPE_AGENT);
        }
    }
}

// ---------------- feats[s][k] = emitW[k] . [h_fwd[s], h_bwd[s]] + emit_b[k] ----------------
__global__ __launch_bounds__(192) void k_feats(const float* __restrict__ hs,
                                               const float* __restrict__ emitW,
                                               const float* __restrict__ emitb,
                                               float* __restrict__ feats) {
    __shared__ float wb[KT][516];
    __shared__ float hb[8][516];
    int tid = threadIdx.x;
    int s0 = blockIdx.x * 8;
    for (int idx = tid; idx < KT * 512; idx += 192) {
        wb[idx >> 9][idx & 511] = emitW[idx];
    }
    for (int idx = tid; idx < 8 * 512; idx += 192) {
        int sl = idx >> 9, jj = idx & 511;
        float v = (jj < 256) ? hs[(long)(s0 + sl) * HD + jj]
                             : hs[(long)(SLEN + s0 + sl) * HD + (jj - 256)];
        hb[sl][jj] = v;
    }
    __syncthreads();
    if (tid < 160) {
        int sl = tid / KT, k = tid % KT;
        float acc = emitb[k];
        for (int jj = 0; jj < 512; jj += 4) {
            float4 wv = *(const float4*)&wb[k][jj];
            float4 hv = *(const float4*)&hb[sl][jj];
            acc += wv.x * hv.x + wv.y * hv.y + wv.z * hv.z + wv.w * hv.w;
        }
        feats[(long)(s0 + sl) * KT + k] = acc;
    }
}

// ---------------- gold path score -> out[1] ----------------
__global__ __launch_bounds__(256) void k_gold(const float* __restrict__ feats,
                                              const int* __restrict__ tags,
                                              const float* __restrict__ trans,
                                              float* __restrict__ out) {
    __shared__ float red[256];
    int tid = threadIdx.x;
    float local = 0.f;
    for (int s2 = tid; s2 < SLEN; s2 += 256) {
        int cur = tags[s2];
        int prev = s2 ? tags[s2 - 1] : START_ID;
        local += trans[cur * KT + prev] + feats[(long)s2 * KT + cur];
    }
    red[tid] = local;
    __syncthreads();
    for (int off = 128; off; off >>= 1) {
        if (tid < off) red[tid] += red[tid + off];
        __syncthreads();
    }
    if (tid == 0) out[1] = red[0] + trans[STOP_ID * KT + tags[SLEN - 1]];
}

// ---------------- CRF: chunk of 16 step-matrices -> one 20x20 log-space matrix ----------------
__global__ __launch_bounds__(512) void k_crf_chunk(const float* __restrict__ feats,
                                                   const float* __restrict__ trans,
                                                   float* __restrict__ mats) {
    __shared__ float T[KT][KT + 1];
    __shared__ float fb[16][KT];
    __shared__ float cur[2][KT][KT + 1];
    int tid = threadIdx.x;
    int t0 = blockIdx.x * 16;
    if (tid < KT * KT) T[tid / KT][tid % KT] = trans[tid];
    for (int idx = tid; idx < 16 * KT; idx += 512) fb[idx / KT][idx % KT] = feats[(long)t0 * KT + idx];
    __syncthreads();
    int i = tid / KT, jc = tid % KT;
    bool act = tid < KT * KT;
    if (act) cur[0][i][jc] = T[i][jc] + fb[0][i];
    __syncthreads();
    for (int m = 1; m < 16; m++) {
        int p = (m - 1) & 1;
        float nv = 0.f;
        if (act) {
            float vs[KT], vmax = -1e30f;
#pragma unroll
            for (int k = 0; k < KT; k++) { vs[k] = T[i][k] + cur[p][k][jc]; vmax = fmaxf(vmax, vs[k]); }
            float sum = 0.f;
#pragma unroll
            for (int k = 0; k < KT; k++) sum += __expf(vs[k] - vmax);
            nv = fb[m][i] + vmax + __logf(sum);
        }
        if (act) cur[p ^ 1][i][jc] = nv;
        __syncthreads();
    }
    if (act) mats[(long)blockIdx.x * (KT * KT) + tid] = cur[1][i][jc];
}

// ---------------- CRF: combine per_block consecutive matrices (left-applied) ----------------
__global__ __launch_bounds__(512) void k_crf_combine(const float* __restrict__ in,
                                                     float* __restrict__ out_mats,
                                                     int per_block,
                                                     const float* __restrict__ trans,
                                                     float* __restrict__ d_out_ptr,
                                                     int finalize) {
    __shared__ float A[KT][KT + 1];
    __shared__ float cur[2][KT][KT + 1];
    int tid = threadIdx.x;
    int b = blockIdx.x;
    int i = tid / KT, jc = tid % KT;
    bool act = tid < KT * KT;
    const float* base = in + (long)b * per_block * (KT * KT);
    if (act) cur[0][i][jc] = base[tid];
    __syncthreads();
    for (int m = 1; m < per_block; m++) {
        int p = (m - 1) & 1;
        if (act) A[i][jc] = base[(long)m * KT * KT + tid];
        __syncthreads();
        float nv = 0.f;
        if (act) {
            float vs[KT], vmax = -1e30f;
#pragma unroll
            for (int k = 0; k < KT; k++) { vs[k] = A[i][k] + cur[p][k][jc]; vmax = fmaxf(vmax, vs[k]); }
            float sum = 0.f;
#pragma unroll
            for (int k = 0; k < KT; k++) sum += __expf(vs[k] - vmax);
            nv = vmax + __logf(sum);
        }
        if (act) cur[p ^ 1][i][jc] = nv;
        __syncthreads();
    }
    int fbuf = (per_block - 1) & 1;
    if (!finalize) {
        if (act) out_mats[(long)b * KT * KT + tid] = cur[fbuf][i][jc];
        return;
    }
    if (tid == 0) {
        float fv[KT];
        for (int ii = 0; ii < KT; ii++) {
            float vs[KT], vmax = -1e30f;
            for (int k = 0; k < KT; k++) {
                float v = cur[fbuf][ii][k] + (k == START_ID ? 0.f : -10000.f);
                vs[k] = v;
                vmax = fmaxf(vmax, v);
            }
            float sum = 0.f;
            for (int k = 0; k < KT; k++) sum += __expf(vs[k] - vmax);
            fv[ii] = vmax + __logf(sum);
        }
        float vs2[KT], vmax = -1e30f;
        for (int ii = 0; ii < KT; ii++) {
            float v = fv[ii] + trans[STOP_ID * KT + ii];
            vs2[ii] = v;
            vmax = fmaxf(vmax, v);
        }
        float sum = 0.f;
        for (int ii = 0; ii < KT; ii++) sum += __expf(vs2[ii] - vmax);
        d_out_ptr[0] = vmax + __logf(sum);
    }
}

extern "C" void kernel_launch(void* const* d_in, const int* in_sizes, int n_in,
                              void* d_out, int out_size, void* d_ws, size_t ws_size,
                              hipStream_t stream) {
    const int* sentence = (const int*)d_in[0];
    const int* tags = (const int*)d_in[1];
    const float* embed = (const float*)d_in[2];
    const float* w_ih_f = (const float*)d_in[3];
    const float* w_hh_f = (const float*)d_in[4];
    const float* b_f = (const float*)d_in[5];
    const float* w_ih_b = (const float*)d_in[6];
    const float* w_hh_b = (const float*)d_in[7];
    const float* b_b = (const float*)d_in[8];
    const float* h0 = (const float*)d_in[9];
    const float* c0 = (const float*)d_in[10];
    const float* emit_W = (const float*)d_in[11];
    const float* emit_b = (const float*)d_in[12];
    const float* transition = (const float*)d_in[13];
    float* out = (float*)d_out;

    char* ws = (char*)d_ws;
    float* zxp = (float*)(ws + 0);                       // 2*4096*1024 f32 = 33,554,432 B
    float* hs = (float*)(ws + 33554432);                 // 2*4096*256 f32  = 8,388,608 B
    float* wT = (float*)(ws + 41943040);                 // 2*256*1024 f32  = 2,097,152 B
    uint32_t* wpack = (uint32_t*)(ws + 44040192);        // 8*64*512 u32    = 1,048,576 B
    float* feats = (float*)(ws + 45088768);              // 4096*20 f32     = 327,680 B
    float* mats = (float*)(ws + 45416448);               // 256*400 f32     = 409,600 B
    float* mats2 = (float*)(ws + 45826048);              // 16*400 f32      = 25,600 B
    float* hglob = (float*)(ws + 45851648);              // 2*2*256 f32     = 4,096 B
    int* flags = (int*)(ws + 45855744);                  // 8 ints (pad 128 B)

    k_transpose_ih<<<dim3(32, 8, 2), 256, 0, stream>>>(w_ih_f, w_ih_b, wT);
    k_pack_hh<<<dim3(64, 8), 512, 0, stream>>>(w_hh_f, w_hh_b, wpack, flags);
    k_zx<<<dim3(256, 2), 256, 0, stream>>>(sentence, embed, wT, b_f, b_b, zxp);
    k_lstm<<<dim3(32), 512, 0, stream>>>(zxp, wpack, h0, c0, hs, hglob, flags);
    k_feats<<<dim3(512), 192, 0, stream>>>(hs, emit_W, emit_b, feats);
    k_gold<<<dim3(1), 256, 0, stream>>>(feats, tags, transition, out);
    k_crf_chunk<<<dim3(256), 512, 0, stream>>>(feats, transition, mats);
    k_crf_combine<<<dim3(16), 512, 0, stream>>>(mats, mats2, 16, transition, out, 0);
    k_crf_combine<<<dim3(1), 512, 0, stream>>>(mats2, nullptr, 16, transition, out, 1);
}